// Round 19
// baseline (93.963 us; speedup 1.0000x reference)
//
#include <hip/hip_runtime.h>
#include <hip/hip_bf16.h>

#define B_N 16384
#define D_K 128
#define NS_DEF 8   // col splits: 512 blocks = exactly one 2-blocks/CU round

typedef __bf16 bf16x8 __attribute__((ext_vector_type(8)));
typedef float f32x4 __attribute__((ext_vector_type(4)));
typedef float f32x2 __attribute__((ext_vector_type(2)));

#if defined(__has_builtin)
#if __has_builtin(__builtin_amdgcn_exp2f)
#define EXP2F(x) __builtin_amdgcn_exp2f(x)
#else
#define EXP2F(x) exp2f(x)
#endif
#else
#define EXP2F(x) exp2f(x)
#endif

__device__ __forceinline__ void gload_lds16(const void* g, void* l) {
  __builtin_amdgcn_global_load_lds(
      (const __attribute__((address_space(1))) unsigned int*)g,
      (__attribute__((address_space(3))) unsigned int*)l, 16, 0, 0);
}

// Agent-coherent 8-byte store/load (global_store/load_dwordx2 sc1): visible
// across XCDs without any cache-wide fence. R15-R17 lesson: __threadfence()
// = buffer_wbl2 + buffer_inv (whole-L2); per-block fences evict live blocks'
// L2 working set. sc1 point-accesses cost nothing.
__device__ __forceinline__ void coh_store(float2* p, float x, float y) {
  unsigned long long bits =
      (unsigned long long)__float_as_uint(x) |
      ((unsigned long long)__float_as_uint(y) << 32);
  __hip_atomic_store((unsigned long long*)p, bits,
                     __ATOMIC_RELAXED, __HIP_MEMORY_SCOPE_AGENT);
}
__device__ __forceinline__ float2 coh_load(const float2* p) {
  unsigned long long b =
      __hip_atomic_load((const unsigned long long*)p,
                        __ATOMIC_RELAXED, __HIP_MEMORY_SCOPE_AGENT);
  return make_float2(__uint_as_float((unsigned)(b & 0xffffffffu)),
                     __uint_as_float((unsigned)(b >> 32)));
}

// ---------------- kernel 1: normalize rows (prescaled by sqrt(1/(T*ln2))), build col
// weights, histogram partials (blocks 0..63), zero completion counters (replay-safe).
__global__ __launch_bounds__(256) void prep_kernel(
    const float* __restrict__ E, const int* __restrict__ labels,
    const int* __restrict__ mask, __hip_bfloat16* __restrict__ Ebf,
    float2* __restrict__ W, int2* __restrict__ histPartial,
    unsigned int* __restrict__ rowCnt, unsigned int* __restrict__ done)
{
  int tid = threadIdx.x;
  int bid = blockIdx.x;
  int gtid = bid * 256 + tid;
  int lane = tid & 63, wv = tid >> 6;

  if (gtid < 64) rowCnt[gtid] = 0u;
  if (gtid == 64) *done = 0u;

  if (gtid < B_N) {
    int lb = labels[gtid];
    float wm = (mask[gtid] != 0) ? 1.0f : 0.0f;
    W[gtid] = make_float2((lb == 0) ? wm : 0.0f, wm);
  }
  if (bid < 64) {   // histogram partials: deterministic, no atomics
    __shared__ int hc[8];
    int c0 = 0, c1 = 0;
    if (mask[gtid] != 0) { if (labels[gtid] == 0) c0 = 1; else c1 = 1; }
    #pragma unroll
    for (int m = 1; m < 64; m <<= 1) { c0 += __shfl_xor(c0, m); c1 += __shfl_xor(c1, m); }
    if (lane == 0) { hc[wv] = c0; hc[4 + wv] = c1; }
    __syncthreads();
    if (tid == 0)
      histPartial[bid] = make_int2(hc[0] + hc[1] + hc[2] + hc[3],
                                   hc[4] + hc[5] + hc[6] + hc[7]);
  }
  {
    int wid = gtid >> 6;
    const float2* E2 = (const float2*)E;
    __hip_bfloat162* O2 = (__hip_bfloat162*)Ebf;
    for (int row = wid; row < B_N; row += 4096) {
      float2 v = E2[row * 64 + lane];
      float ss = v.x * v.x + v.y * v.y;
      #pragma unroll
      for (int m = 1; m < 64; m <<= 1) ss += __shfl_xor(ss, m);
      // sqrt(14.426950408889634) = sqrt(1/(0.1*ln2)); folded into both operands
      float sc = 3.7982826f / fmaxf(sqrtf(ss), 1e-12f);
      __hip_bfloat162 h;
      h.x = __float2bfloat16(v.x * sc);
      h.y = __float2bfloat16(v.y * sc);
      O2[row * 64 + lane] = h;
    }
  }
}

// ---------------- tile body with explicit cross-nf software pipeline:
// nf's MFMA cluster issues BEFORE nf-1's epilogue (exp+pk_fma on nf-1's results),
// breaking the per-nf MFMA->exp serial chain at the issue point. Deferred state:
// one f32x4[4] + f32x2 + int (~19 VGPRs). All indices compile-time (full unroll).
template<bool DIAG>
__device__ __forceinline__ void tile_compute(
    const char* lds, const char* ldsW, const bf16x8 a[4][4],
    int C0loc, int colBase, int lane, int WR0, f32x2 acc[4][4])
{
  const int l15 = lane & 15, lg = lane >> 4;
  f32x4 cPrev[4];
  f32x2 wvPrev = {0.f, 0.f};
  int colgPrev = 0;
  #pragma unroll
  for (int nf = 0; nf < 4; ++nf) {
    int col = nf * 16 + l15;
    int colg = colBase + C0loc + col;
    f32x2 wv = *(const f32x2*)(ldsW + ((C0loc + col) << 3));  // LDS broadcast
    bf16x8 b[4];
    #pragma unroll
    for (int kk = 0; kk < 4; ++kk) {
      int addr = col * 256 + (((kk * 4 + lg) ^ l15) << 4);    // 2-way banks (free)
      b[kk] = *(const bf16x8*)(lds + addr);
    }
    f32x4 c[4];
    __builtin_amdgcn_s_setprio(1);
    #pragma unroll
    for (int mf = 0; mf < 4; ++mf) {
      f32x4 t = {0.f, 0.f, 0.f, 0.f};
      #pragma unroll
      for (int kk = 0; kk < 4; ++kk)
        t = __builtin_amdgcn_mfma_f32_16x16x32_bf16(a[mf][kk], b[kk], t, 0, 0, 0);
      c[mf] = t;
    }
    __builtin_amdgcn_s_setprio(0);
    if (nf > 0) {   // epilogue of nf-1 overlaps nf's in-flight MFMAs
      #pragma unroll
      for (int mf = 0; mf < 4; ++mf) {
        #pragma unroll
        for (int r = 0; r < 4; ++r) {
          float p = EXP2F(cPrev[mf][r]);   // exp(sim/T), scale folded into operands
          if (DIAG) {
            int rowg = WR0 + mf * 16 + lg * 4 + r;  // verified C/D layout
            p = (rowg == colgPrev - l15 + (colgPrev & 15) + ((colgPrev - colBase - C0loc) & ~15) + colBase + C0loc - ((colgPrev - colBase - C0loc) & ~15)) ? 0.0f : p;
          }
          acc[mf][r] += wvPrev * p;        // v_pk_fma_f32: (label-0, total)
        }
      }
    }
    #pragma unroll
    for (int mf = 0; mf < 4; ++mf) cPrev[mf] = c[mf];
    wvPrev = wv;
    colgPrev = colg;
  }
  // final nf's epilogue (before the drain/barrier, as before)
  #pragma unroll
  for (int mf = 0; mf < 4; ++mf) {
    #pragma unroll
    for (int r = 0; r < 4; ++r) {
      float p = EXP2F(cPrev[mf][r]);
      if (DIAG) {
        int rowg = WR0 + mf * 16 + lg * 4 + r;
        p = (rowg == colgPrev) ? 0.0f : p;
      }
      acc[mf][r] += wvPrev * p;
    }
  }
}

// Fix the over-clever DIAG expression above: colgPrev IS the full global col.
// (The expression reduces to colgPrev; keep a clean specialization instead.)
template<>
__device__ __forceinline__ void tile_compute<true>(
    const char* lds, const char* ldsW, const bf16x8 a[4][4],
    int C0loc, int colBase, int lane, int WR0, f32x2 acc[4][4])
{
  const int l15 = lane & 15, lg = lane >> 4;
  f32x4 cPrev[4];
  f32x2 wvPrev = {0.f, 0.f};
  int colgPrev = 0;
  #pragma unroll
  for (int nf = 0; nf < 4; ++nf) {
    int col = nf * 16 + l15;
    int colg = colBase + C0loc + col;
    f32x2 wv = *(const f32x2*)(ldsW + ((C0loc + col) << 3));
    bf16x8 b[4];
    #pragma unroll
    for (int kk = 0; kk < 4; ++kk) {
      int addr = col * 256 + (((kk * 4 + lg) ^ l15) << 4);
      b[kk] = *(const bf16x8*)(lds + addr);
    }
    f32x4 c[4];
    __builtin_amdgcn_s_setprio(1);
    #pragma unroll
    for (int mf = 0; mf < 4; ++mf) {
      f32x4 t = {0.f, 0.f, 0.f, 0.f};
      #pragma unroll
      for (int kk = 0; kk < 4; ++kk)
        t = __builtin_amdgcn_mfma_f32_16x16x32_bf16(a[mf][kk], b[kk], t, 0, 0, 0);
      c[mf] = t;
    }
    __builtin_amdgcn_s_setprio(0);
    if (nf > 0) {
      #pragma unroll
      for (int mf = 0; mf < 4; ++mf) {
        #pragma unroll
        for (int r = 0; r < 4; ++r) {
          float p = EXP2F(cPrev[mf][r]);
          int rowg = WR0 + mf * 16 + lg * 4 + r;
          p = (rowg == colgPrev) ? 0.0f : p;
          acc[mf][r] += wvPrev * p;
        }
      }
    }
    #pragma unroll
    for (int mf = 0; mf < 4; ++mf) cPrev[mf] = c[mf];
    wvPrev = wv;
    colgPrev = colg;
  }
  #pragma unroll
  for (int mf = 0; mf < 4; ++mf) {
    #pragma unroll
    for (int r = 0; r < 4; ++r) {
      float p = EXP2F(cPrev[mf][r]);
      int rowg = WR0 + mf * 16 + lg * 4 + r;
      p = (rowg == colgPrev) ? 0.0f : p;
      acc[mf][r] += wvPrev * p;
    }
  }
}

template<>
__device__ __forceinline__ void tile_compute<false>(
    const char* lds, const char* ldsW, const bf16x8 a[4][4],
    int C0loc, int colBase, int lane, int WR0, f32x2 acc[4][4])
{
  const int l15 = lane & 15, lg = lane >> 4;
  f32x4 cPrev[4];
  f32x2 wvPrev = {0.f, 0.f};
  #pragma unroll
  for (int nf = 0; nf < 4; ++nf) {
    int col = nf * 16 + l15;
    f32x2 wv = *(const f32x2*)(ldsW + ((C0loc + col) << 3));
    bf16x8 b[4];
    #pragma unroll
    for (int kk = 0; kk < 4; ++kk) {
      int addr = col * 256 + (((kk * 4 + lg) ^ l15) << 4);
      b[kk] = *(const bf16x8*)(lds + addr);
    }
    f32x4 c[4];
    __builtin_amdgcn_s_setprio(1);
    #pragma unroll
    for (int mf = 0; mf < 4; ++mf) {
      f32x4 t = {0.f, 0.f, 0.f, 0.f};
      #pragma unroll
      for (int kk = 0; kk < 4; ++kk)
        t = __builtin_amdgcn_mfma_f32_16x16x32_bf16(a[mf][kk], b[kk], t, 0, 0, 0);
      c[mf] = t;
    }
    __builtin_amdgcn_s_setprio(0);
    if (nf > 0) {
      #pragma unroll
      for (int mf = 0; mf < 4; ++mf) {
        #pragma unroll
        for (int r = 0; r < 4; ++r) {
          float p = EXP2F(cPrev[mf][r]);
          acc[mf][r] += wvPrev * p;
        }
      }
    }
    #pragma unroll
    for (int mf = 0; mf < 4; ++mf) cPrev[mf] = c[mf];
    wvPrev = wv;
  }
  #pragma unroll
  for (int mf = 0; mf < 4; ++mf) {
    #pragma unroll
    for (int r = 0; r < 4; ++r) {
      float p = EXP2F(cPrev[mf][r]);
      acc[mf][r] += wvPrev * p;
    }
  }
}

// ---------------- kernel 2: Gram + exp + row-sums, fused loss tail (R18 sc1 protocol)
__global__ __launch_bounds__(256, 2) void gemm_kernel(
    const __hip_bfloat16* __restrict__ Ebf, const float2* __restrict__ W,
    const int* __restrict__ labels, const int* __restrict__ mask,
    float2* __restrict__ SW, int NS, int colsPerSplit,
    const int2* __restrict__ histPartial, float2* __restrict__ partialF,
    unsigned int* __restrict__ rowCnt, unsigned int* __restrict__ done,
    float* __restrict__ out)
{
  __shared__ alignas(16) char smem[49152];
  char* ldsW  = smem;            // 16 KB: w(col) for cps<=2048
  char* tiles = smem + 16384;    // 2 x 16 KB double buffer

  const int tid = threadIdx.x;
  const int lane = tid & 63;
  const int w = tid >> 6;
  const int Rblk = blockIdx.x;
  const int R0 = Rblk * 256;
  const int WR0 = R0 + w * 64;
  const int l15 = lane & 15, lg = lane >> 4;

  bf16x8 a[4][4];
  #pragma unroll
  for (int mf = 0; mf < 4; ++mf)
    #pragma unroll
    for (int kk = 0; kk < 4; ++kk) {
      int row = WR0 + mf * 16 + l15;
      a[mf][kk] = *(const bf16x8*)(Ebf + (size_t)row * D_K + kk * 32 + lg * 8);
    }

  int goff[4], loff[4];
  #pragma unroll
  for (int i = 0; i < 4; ++i) {
    int q = i * 4 + w;
    int col = q * 4 + lg;
    int cc = l15 ^ (col & 15);    // inverse of the l15 read swizzle
    goff[i] = col * D_K + cc * 8;
    loff[i] = q * 1024;
  }

  f32x2 acc[4][4] = {};
  const int colBase = blockIdx.y * colsPerSplit;
  const int nt = colsPerSplit >> 6;

  {
    const char* wsrc = (const char*)(W + colBase);
    for (int i = tid; i < (colsPerSplit >> 1); i += 256)
      gload_lds16(wsrc + i * 16, ldsW + i * 16);
    const __hip_bfloat16* src0 = Ebf + (size_t)colBase * D_K;
    #pragma unroll
    for (int i = 0; i < 4; ++i) gload_lds16(src0 + goff[i], tiles + loff[i]);
  }
  asm volatile("s_waitcnt vmcnt(0)" ::: "memory");
  __builtin_amdgcn_s_barrier();

  int cur = 0;
  for (int t = 0; t < nt; ++t) {
    if (t + 1 < nt) {
      const __hip_bfloat16* src = Ebf + (size_t)(colBase + ((t + 1) << 6)) * D_K;
      char* dst = tiles + ((cur ^ 1) << 14);
      #pragma unroll
      for (int i = 0; i < 4; ++i) gload_lds16(src + goff[i], dst + loff[i]);
    }
    const int C0loc = t << 6;
    const int Cg = colBase + C0loc;
    const bool diag = (Cg < R0 + 256) && (Cg + 64 > R0);
    if (diag) tile_compute<true >(tiles + (cur << 14), ldsW, a, C0loc, colBase, lane, WR0, acc);
    else      tile_compute<false>(tiles + (cur << 14), ldsW, a, C0loc, colBase, lane, WR0, acc);
    asm volatile("s_waitcnt vmcnt(0)" ::: "memory");
    __builtin_amdgcn_s_barrier();
    cur ^= 1;
  }

  // reduce the 16 lanes, then agent-coherent store (sc1, no fence needed)
  #pragma unroll
  for (int mf = 0; mf < 4; ++mf) {
    #pragma unroll
    for (int r = 0; r < 4; ++r) {
      float s0 = acc[mf][r].x, tt = acc[mf][r].y;
      #pragma unroll
      for (int m = 1; m < 16; m <<= 1) {
        s0 += __shfl_xor(s0, m);
        tt += __shfl_xor(tt, m);
      }
      if (l15 == 0) {
        int rowg = WR0 + mf * 16 + lg * 4 + r;
        coh_store(&SW[(size_t)blockIdx.y * B_N + rowg], s0, tt);
      }
    }
  }

  // ---------------- fused loss tail (last-of-NS per row-block, then last-of-64)
  __shared__ unsigned int sTicket;
  __syncthreads();                       // drains every wave's sc1 stores (vmcnt 0)
  if (tid == 0) sTicket = atomicAdd(&rowCnt[Rblk], 1u);
  __syncthreads();
  if (sTicket == (unsigned)(NS - 1)) {   // this block finalizes rows R0..R0+255
    int* cs = (int*)smem;
    float* st = (float*)(smem + 64);
    float* sn = (float*)(smem + 128);
    if (tid < 64) {
      int2 h = histPartial[tid];
      int a0 = h.x, b0 = h.y;
      #pragma unroll
      for (int m = 1; m < 64; m <<= 1) { a0 += __shfl_xor(a0, m); b0 += __shfl_xor(b0, m); }
      if (tid == 0) { cs[0] = a0; cs[1] = b0; }
    }
    __syncthreads();
    int cnt0 = cs[0], cnt1 = cs[1];
    int r = R0 + tid;
    float s0 = 0.f, tt = 0.f;
    for (int s = 0; s < NS; ++s) {       // fixed ascending order: deterministic
      float2 v = coh_load(&SW[(size_t)s * B_N + r]);
      s0 += v.x; tt += v.y;
    }
    int lb = labels[r];
    float pos = (lb == 0) ? s0 : (tt - s0);
    int cnt = (lb == 0) ? cnt0 : cnt1;
    float tot = 0.f, nv = 0.f;
    if (mask[r] != 0 && cnt > 1) {
      tot = logf(tt + 1e-8f) - logf(pos);
      nv = 1.f;
    }
    #pragma unroll
    for (int m = 1; m < 64; m <<= 1) { tot += __shfl_xor(tot, m); nv += __shfl_xor(nv, m); }
    if (lane == 0) { st[w] = tot; sn[w] = nv; }
    __syncthreads();
    __shared__ unsigned int sTicket2;
    if (tid == 0) {
      coh_store(&partialF[Rblk],
                st[0] + st[1] + st[2] + st[3],
                sn[0] + sn[1] + sn[2] + sn[3]);
      asm volatile("s_waitcnt vmcnt(0)" ::: "memory");
      sTicket2 = atomicAdd(done, 1u);
    }
    __syncthreads();
    if (sTicket2 == 63u) {
      if (tid < 64) {
        float2 p = coh_load(&partialF[tid]);
        float t2 = p.x, n2 = p.y;
        #pragma unroll
        for (int m = 1; m < 64; m <<= 1) { t2 += __shfl_xor(t2, m); n2 += __shfl_xor(n2, m); }
        if (tid == 0) out[0] = (n2 > 0.f) ? t2 / fmaxf(n2, 1.f) : 0.f;
      }
    }
  }
}

extern "C" void kernel_launch(void* const* d_in, const int* in_sizes, int n_in,
                              void* d_out, int out_size, void* d_ws, size_t ws_size,
                              hipStream_t stream)
{
  const float* E = (const float*)d_in[0];
  const int* labels = (const int*)d_in[1];
  const int* mask = (const int*)d_in[2];

  char* ws = (char*)d_ws;
  __hip_bfloat16* Ebf = (__hip_bfloat16*)ws;                       // 4 MB
  float2* W = (float2*)(ws + (size_t)B_N * D_K * 2);               // 128 KB
  float2* SW = (float2*)(ws + (size_t)B_N * D_K * 2 + (size_t)B_N * 8);
  size_t base = (size_t)B_N * D_K * 2 + (size_t)B_N * 8;

  int NS = NS_DEF;  // shrink if workspace tight (ldsW sized for cps<=2048)
  while (NS > 1 && base + (size_t)NS * B_N * 8 + 4096 > ws_size) NS >>= 1;
  int cps = B_N / NS;
  char* aux = ws + base + (size_t)NS * B_N * 8;
  float2* partialF = (float2*)aux;                     // 64 x 8 B
  int2* histPartial = (int2*)(aux + 512);              // 64 x 8 B
  unsigned int* rowCnt = (unsigned int*)(aux + 1024);  // 64 x 4 B
  unsigned int* done = (unsigned int*)(aux + 1280);    // 4 B

  prep_kernel<<<1024, 256, 0, stream>>>(E, labels, mask, Ebf, W,
                                        histPartial, rowCnt, done);
  dim3 g2(B_N / 256, NS);   // (64, 8) = 512 blocks = one full 2-blocks/CU round
  gemm_kernel<<<g2, 256, 0, stream>>>(Ebf, W, labels, mask, SW, NS, cps,
                                      histPartial, partialF, rowCnt, done,
                                      (float*)d_out);
}

// Round 20
// 92.912 us; speedup vs baseline: 1.0113x; 1.0113x over previous
//
#include <hip/hip_runtime.h>
#include <hip/hip_bf16.h>

#define B_N 16384
#define D_K 128
#define NS_DEF 8   // col splits: 512 blocks = exactly one 2-blocks/CU round

typedef __bf16 bf16x8 __attribute__((ext_vector_type(8)));
typedef float f32x4 __attribute__((ext_vector_type(4)));
typedef float f32x2 __attribute__((ext_vector_type(2)));

#if defined(__has_builtin)
#if __has_builtin(__builtin_amdgcn_exp2f)
#define EXP2F(x) __builtin_amdgcn_exp2f(x)
#else
#define EXP2F(x) exp2f(x)
#endif
#else
#define EXP2F(x) exp2f(x)
#endif

__device__ __forceinline__ void gload_lds16(const void* g, void* l) {
  __builtin_amdgcn_global_load_lds(
      (const __attribute__((address_space(1))) unsigned int*)g,
      (__attribute__((address_space(3))) unsigned int*)l, 16, 0, 0);
}

// Agent-coherent 8-byte store/load (global_store/load_dwordx2 sc1): visible
// across XCDs without any cache-wide fence. R15-R17 lesson: __threadfence() =
// buffer_wbl2 + buffer_inv (whole-L2); per-block fences evict live blocks'
// L2 working set (+20-45us). sc1 point-accesses cost ~nothing.
__device__ __forceinline__ void coh_store(float2* p, float x, float y) {
  unsigned long long bits =
      (unsigned long long)__float_as_uint(x) |
      ((unsigned long long)__float_as_uint(y) << 32);
  __hip_atomic_store((unsigned long long*)p, bits,
                     __ATOMIC_RELAXED, __HIP_MEMORY_SCOPE_AGENT);
}
__device__ __forceinline__ float2 coh_load(const float2* p) {
  unsigned long long b =
      __hip_atomic_load((const unsigned long long*)p,
                        __ATOMIC_RELAXED, __HIP_MEMORY_SCOPE_AGENT);
  return make_float2(__uint_as_float((unsigned)(b & 0xffffffffu)),
                     __uint_as_float((unsigned)(b >> 32)));
}

// ---------------- kernel 1: normalize rows (prescaled by sqrt(1/(T*ln2))), build col
// weights, histogram partials (blocks 0..63), zero completion counters (replay-safe).
__global__ __launch_bounds__(256) void prep_kernel(
    const float* __restrict__ E, const int* __restrict__ labels,
    const int* __restrict__ mask, __hip_bfloat16* __restrict__ Ebf,
    float2* __restrict__ W, int2* __restrict__ histPartial,
    unsigned int* __restrict__ rowCnt, unsigned int* __restrict__ done)
{
  int tid = threadIdx.x;
  int bid = blockIdx.x;
  int gtid = bid * 256 + tid;
  int lane = tid & 63, wv = tid >> 6;

  if (gtid < 64) rowCnt[gtid] = 0u;
  if (gtid == 64) *done = 0u;

  if (gtid < B_N) {
    int lb = labels[gtid];
    float wm = (mask[gtid] != 0) ? 1.0f : 0.0f;
    W[gtid] = make_float2((lb == 0) ? wm : 0.0f, wm);
  }
  if (bid < 64) {   // histogram partials: deterministic, no atomics
    __shared__ int hc[8];
    int c0 = 0, c1 = 0;
    if (mask[gtid] != 0) { if (labels[gtid] == 0) c0 = 1; else c1 = 1; }
    #pragma unroll
    for (int m = 1; m < 64; m <<= 1) { c0 += __shfl_xor(c0, m); c1 += __shfl_xor(c1, m); }
    if (lane == 0) { hc[wv] = c0; hc[4 + wv] = c1; }
    __syncthreads();
    if (tid == 0)
      histPartial[bid] = make_int2(hc[0] + hc[1] + hc[2] + hc[3],
                                   hc[4] + hc[5] + hc[6] + hc[7]);
  }
  {
    int wid = gtid >> 6;
    const float2* E2 = (const float2*)E;
    __hip_bfloat162* O2 = (__hip_bfloat162*)Ebf;
    for (int row = wid; row < B_N; row += 4096) {
      float2 v = E2[row * 64 + lane];
      float ss = v.x * v.x + v.y * v.y;
      #pragma unroll
      for (int m = 1; m < 64; m <<= 1) ss += __shfl_xor(ss, m);
      // sqrt(14.426950408889634) = sqrt(1/(0.1*ln2)); folded into both operands
      float sc = 3.7982826f / fmaxf(sqrtf(ss), 1e-12f);
      __hip_bfloat162 h;
      h.x = __float2bfloat16(v.x * sc);
      h.y = __float2bfloat16(v.y * sc);
      O2[row * 64 + lane] = h;
    }
  }
}

// ---------------- tile body (R10-proven: l15 swizzle, conflicts==0 verified)
template<bool DIAG>
__device__ __forceinline__ void tile_compute(
    const char* lds, const char* ldsW, const bf16x8 a[4][4],
    int C0loc, int colBase, int lane, int WR0, f32x2 acc[4][4])
{
  const int l15 = lane & 15, lg = lane >> 4;
  #pragma unroll
  for (int nf = 0; nf < 4; ++nf) {
    int col = nf * 16 + l15;
    int colg = colBase + C0loc + col;
    f32x2 wv = *(const f32x2*)(ldsW + ((C0loc + col) << 3));  // LDS broadcast
    bf16x8 b[4];
    #pragma unroll
    for (int kk = 0; kk < 4; ++kk) {
      int addr = col * 256 + (((kk * 4 + lg) ^ l15) << 4);    // 2-way banks (free)
      b[kk] = *(const bf16x8*)(lds + addr);
    }
    f32x4 c[4];
    __builtin_amdgcn_s_setprio(1);
    #pragma unroll
    for (int mf = 0; mf < 4; ++mf) {
      f32x4 t = {0.f, 0.f, 0.f, 0.f};
      #pragma unroll
      for (int kk = 0; kk < 4; ++kk)
        t = __builtin_amdgcn_mfma_f32_16x16x32_bf16(a[mf][kk], b[kk], t, 0, 0, 0);
      c[mf] = t;
    }
    __builtin_amdgcn_s_setprio(0);
    #pragma unroll
    for (int mf = 0; mf < 4; ++mf) {
      #pragma unroll
      for (int r = 0; r < 4; ++r) {
        float p = EXP2F(c[mf][r]);     // exp(sim/T), scale folded into operands
        if (DIAG) {
          int rowg = WR0 + mf * 16 + lg * 4 + r;  // verified C/D layout
          p = (rowg == colg) ? 0.0f : p;
        }
        acc[mf][r] += wv * p;          // v_pk_fma_f32: (label-0 sum, total sum)
      }
    }
  }
}

// ---------------- kernel 2: Gram + exp + row-sums, fused per-row-block loss tail.
// Cross-block protocol with ZERO __threadfence: SW / partialF written with
// agent-coherent (sc1) stores -> device-visible once vmcnt drains (guaranteed
// by __syncthreads before the ticket). Readers use sc1 loads. Tickets are
// device-scope atomic RMWs at the coherence point. Bit-deterministic: every
// cell written once, summed in fixed order.
__global__ __launch_bounds__(256, 2) void gemm_kernel(
    const __hip_bfloat16* __restrict__ Ebf, const float2* __restrict__ W,
    const int* __restrict__ labels, const int* __restrict__ mask,
    float2* __restrict__ SW, int NS, int colsPerSplit,
    const int2* __restrict__ histPartial, float2* __restrict__ partialF,
    unsigned int* __restrict__ rowCnt, unsigned int* __restrict__ done,
    float* __restrict__ out)
{
  __shared__ alignas(16) char smem[49152];
  char* ldsW  = smem;            // 16 KB: w(col) for cps<=2048
  char* tiles = smem + 16384;    // 2 x 16 KB double buffer

  const int tid = threadIdx.x;
  const int lane = tid & 63;
  const int w = tid >> 6;
  const int Rblk = blockIdx.x;
  const int R0 = Rblk * 256;
  const int WR0 = R0 + w * 64;
  const int l15 = lane & 15, lg = lane >> 4;

  // A fragments: 4 m-frags x 4 k-steps, held in VGPRs for the whole col loop
  bf16x8 a[4][4];
  #pragma unroll
  for (int mf = 0; mf < 4; ++mf)
    #pragma unroll
    for (int kk = 0; kk < 4; ++kk) {
      int row = WR0 + mf * 16 + l15;
      a[mf][kk] = *(const bf16x8*)(Ebf + (size_t)row * D_K + kk * 32 + lg * 8);
    }

  // staging offsets: linear LDS dest, full-4-bit inverse swizzle on global source
  int goff[4], loff[4];
  #pragma unroll
  for (int i = 0; i < 4; ++i) {
    int q = i * 4 + w;            // 1KB chunk-group id 0..15 (16KB tile)
    int col = q * 4 + lg;         // tile-local col this lane feeds (0..63)
    int cc = l15 ^ (col & 15);    // inverse of the l15 read swizzle
    goff[i] = col * D_K + cc * 8; // bf16 elements
    loff[i] = q * 1024;           // wave-uniform LDS base (bytes)
  }

  f32x2 acc[4][4] = {};
  const int colBase = blockIdx.y * colsPerSplit;
  const int nt = colsPerSplit >> 6;

  // prologue: stage W slice + tile 0, drain, rendezvous
  {
    const char* wsrc = (const char*)(W + colBase);
    for (int i = tid; i < (colsPerSplit >> 1); i += 256)
      gload_lds16(wsrc + i * 16, ldsW + i * 16);
    const __hip_bfloat16* src0 = Ebf + (size_t)colBase * D_K;
    #pragma unroll
    for (int i = 0; i < 4; ++i) gload_lds16(src0 + goff[i], tiles + loff[i]);
  }
  asm volatile("s_waitcnt vmcnt(0)" ::: "memory");
  __builtin_amdgcn_s_barrier();

  int cur = 0;
  for (int t = 0; t < nt; ++t) {
    if (t + 1 < nt) {   // prefetch next tile into the other buffer (2-phase)
      const __hip_bfloat16* src = Ebf + (size_t)(colBase + ((t + 1) << 6)) * D_K;
      char* dst = tiles + ((cur ^ 1) << 14);
      #pragma unroll
      for (int i = 0; i < 4; ++i) gload_lds16(src + goff[i], dst + loff[i]);
    }
    const int C0loc = t << 6;
    const int Cg = colBase + C0loc;
    const bool diag = (Cg < R0 + 256) && (Cg + 64 > R0);
    if (diag) tile_compute<true >(tiles + (cur << 14), ldsW, a, C0loc, colBase, lane, WR0, acc);
    else      tile_compute<false>(tiles + (cur << 14), ldsW, a, C0loc, colBase, lane, WR0, acc);
    asm volatile("s_waitcnt vmcnt(0)" ::: "memory");
    __builtin_amdgcn_s_barrier();
    cur ^= 1;
  }

  // reduce the 16 lanes, then agent-coherent store (sc1, no fence needed)
  #pragma unroll
  for (int mf = 0; mf < 4; ++mf) {
    #pragma unroll
    for (int r = 0; r < 4; ++r) {
      float s0 = acc[mf][r].x, tt = acc[mf][r].y;
      #pragma unroll
      for (int m = 1; m < 16; m <<= 1) {
        s0 += __shfl_xor(s0, m);
        tt += __shfl_xor(tt, m);
      }
      if (l15 == 0) {
        int rowg = WR0 + mf * 16 + lg * 4 + r;
        coh_store(&SW[(size_t)blockIdx.y * B_N + rowg], s0, tt);
      }
    }
  }

  // ---------------- fused loss tail (last-of-NS per row-block, then last-of-64)
  __shared__ unsigned int sTicket;
  __syncthreads();                       // drains every wave's sc1 stores (vmcnt 0)
  if (tid == 0) sTicket = atomicAdd(&rowCnt[Rblk], 1u);
  __syncthreads();
  if (sTicket == (unsigned)(NS - 1)) {   // this block finalizes rows R0..R0+255
    int* cs = (int*)smem;                // smem reuse (post-loop, post-sync)
    float* st = (float*)(smem + 64);
    float* sn = (float*)(smem + 128);
    // histogram totals from prep partials (cross-kernel: plain loads fine)
    if (tid < 64) {
      int2 h = histPartial[tid];
      int a0 = h.x, b0 = h.y;
      #pragma unroll
      for (int m = 1; m < 64; m <<= 1) { a0 += __shfl_xor(a0, m); b0 += __shfl_xor(b0, m); }
      if (tid == 0) { cs[0] = a0; cs[1] = b0; }
    }
    __syncthreads();
    int cnt0 = cs[0], cnt1 = cs[1];
    int r = R0 + tid;                    // one row per thread
    float s0 = 0.f, tt = 0.f;
    for (int s = 0; s < NS; ++s) {       // fixed ascending order: deterministic
      float2 v = coh_load(&SW[(size_t)s * B_N + r]);   // sc1: bypass stale caches
      s0 += v.x; tt += v.y;
    }
    int lb = labels[r];
    float pos = (lb == 0) ? s0 : (tt - s0);
    int cnt = (lb == 0) ? cnt0 : cnt1;
    float tot = 0.f, nv = 0.f;
    if (mask[r] != 0 && cnt > 1) {
      // den = pos + neg = tt (diag excluded); loss = log(den+EPS) - log(pos)
      tot = logf(tt + 1e-8f) - logf(pos);
      nv = 1.f;
    }
    #pragma unroll
    for (int m = 1; m < 64; m <<= 1) { tot += __shfl_xor(tot, m); nv += __shfl_xor(nv, m); }
    if (lane == 0) { st[w] = tot; sn[w] = nv; }
    __syncthreads();
    __shared__ unsigned int sTicket2;
    if (tid == 0) {
      coh_store(&partialF[Rblk],
                st[0] + st[1] + st[2] + st[3],
                sn[0] + sn[1] + sn[2] + sn[3]);
      asm volatile("s_waitcnt vmcnt(0)" ::: "memory");  // partialF store complete
      sTicket2 = atomicAdd(done, 1u);
    }
    __syncthreads();
    if (sTicket2 == 63u) {               // last row-block finalizes the scalar
      if (tid < 64) {
        float2 p = coh_load(&partialF[tid]);   // fixed order + fixed shuffle tree
        float t2 = p.x, n2 = p.y;
        #pragma unroll
        for (int m = 1; m < 64; m <<= 1) { t2 += __shfl_xor(t2, m); n2 += __shfl_xor(n2, m); }
        if (tid == 0) out[0] = (n2 > 0.f) ? t2 / fmaxf(n2, 1.f) : 0.f;
      }
    }
  }
}

extern "C" void kernel_launch(void* const* d_in, const int* in_sizes, int n_in,
                              void* d_out, int out_size, void* d_ws, size_t ws_size,
                              hipStream_t stream)
{
  const float* E = (const float*)d_in[0];
  const int* labels = (const int*)d_in[1];
  const int* mask = (const int*)d_in[2];

  char* ws = (char*)d_ws;
  __hip_bfloat16* Ebf = (__hip_bfloat16*)ws;                       // 4 MB
  float2* W = (float2*)(ws + (size_t)B_N * D_K * 2);               // 128 KB
  float2* SW = (float2*)(ws + (size_t)B_N * D_K * 2 + (size_t)B_N * 8);
  size_t base = (size_t)B_N * D_K * 2 + (size_t)B_N * 8;

  int NS = NS_DEF;  // shrink if workspace tight (ldsW sized for cps<=2048)
  while (NS > 1 && base + (size_t)NS * B_N * 8 + 4096 > ws_size) NS >>= 1;
  int cps = B_N / NS;
  char* aux = ws + base + (size_t)NS * B_N * 8;
  float2* partialF = (float2*)aux;                     // 64 x 8 B
  int2* histPartial = (int2*)(aux + 512);              // 64 x 8 B
  unsigned int* rowCnt = (unsigned int*)(aux + 1024);  // 64 x 4 B
  unsigned int* done = (unsigned int*)(aux + 1280);    // 4 B

  prep_kernel<<<1024, 256, 0, stream>>>(E, labels, mask, Ebf, W,
                                        histPartial, rowCnt, done);
  dim3 g2(B_N / 256, NS);   // (64, 8) = 512 blocks = one full 2-blocks/CU round
  gemm_kernel<<<g2, 256, 0, stream>>>(Ebf, W, labels, mask, SW, NS, cps,
                                      histPartial, partialF, rowCnt, done,
                                      (float*)d_out);
}